// Round 1
// 932.948 us; speedup vs baseline: 1.0052x; 1.0052x over previous
//
#include <hip/hip_runtime.h>
#include <cstdint>

#define B_ 64
#define N_ 512
#define D_ 256
#define L_ 4

typedef __bf16 bf16;
typedef __attribute__((ext_vector_type(8))) __bf16 bf16x8;
typedef __attribute__((ext_vector_type(4))) __bf16 bf16x4;
typedef __attribute__((ext_vector_type(4))) float f32x4;

#define MFMA16(a, b, c) __builtin_amdgcn_mfma_f32_16x16x32_bf16((a), (b), (c), 0, 0, 0)

__device__ __forceinline__ float sigmoidf_(float z) {
  return 1.0f / (1.0f + __expf(-z));
}

// ---------------------------------------------------------------------------
// gat_layer: one block per (32-row strip, batch); full layer fused.
// Grid is 1-D (1024) with a bijective XCD swizzle: wg%8 selects the XCD
// (round-robin dispatch), so lid=(wg%8)*128+wg/8 gives each XCD 128
// consecutive logical blocks = 8 complete batches. All xb/xT B-operand
// streams and the layer-(l-1) -> layer-l producer/consumer pairs become
// XCD-local L2 traffic. Same map used by init_x and final_proj.
// Phases:
//  p0: q = x@Wa^T+ba         p1: P = sigmoid(q@xb^T) masked (LDS)
//  p2: rowsum -> normalize; f32 kept in regs, nt-stored AFTER the barrier
//  p3: x' = P@x (xT streamed)  p4: h = relu(x'@W0^T+b0)
//  p5: x = relu(h@W1^T+b1) + resid -> xb_out, xT_out
// All global B-operands are prefetched in 16-load register chunks (MLP).
// LDS ~52 KB -> 3 blocks/CU.
// ---------------------------------------------------------------------------
__global__ __launch_bounds__(256, 3) void gat_layer(
    const bf16* __restrict__ xb_in, const bf16* __restrict__ xT_in,
    bf16* __restrict__ xb_out, bf16* __restrict__ xT_out,
    const bf16* __restrict__ Wa, const float* __restrict__ ba,
    const bf16* __restrict__ W0, const float* __restrict__ b0,
    const bf16* __restrict__ W1, const float* __restrict__ b1,
    const float* __restrict__ adj, const unsigned short* __restrict__ bits_in,
    unsigned short* __restrict__ bits_out, float* __restrict__ outA)
{
  __shared__ bf16 qs[32 * 264];     // q / x' strip (A-layout)
  __shared__ bf16 xps[32 * 520];    // x strip -> P -> h
  __shared__ float psum[4][32];
  __shared__ float rinvs[32];
  __shared__ unsigned int bits_s[512];  // 32 rows x 32 uint16 pieces

  const int tid = threadIdx.x, w = tid >> 6, lane = tid & 63;
  const int l16 = lane & 15, quad = lane >> 4;
  // bijective XCD swizzle: wg%8 -> XCD, 128 consecutive lids per XCD
  const int wg = blockIdx.x;
  const int lid = (wg & 7) * 128 + (wg >> 3);
  const int b = lid >> 4;
  const int row0 = (lid & 15) * 32;

  // ---- stage x strip [32][256] -> xps (stride 264) ----
#pragma unroll
  for (int e = 0; e < 4; ++e) {
    const int cc = tid + e * 256;
    const int r = cc >> 5, cg = cc & 31;
    *(bf16x8*)&xps[r * 264 + cg * 8] =
        *(const bf16x8*)(xb_in + ((size_t)(b * N_ + row0 + r)) * D_ + cg * 8);
  }
  if (bits_in) {  // preload this strip's adjacency bitmask (2 KB)
#pragma unroll
    for (int e = 0; e < 2; ++e) {
      const int t = tid + e * 256;  // t = r*16 + k
      bits_s[t] = ((const unsigned int*)bits_in)[((size_t)b * N_ + row0) * 16 + t];
    }
  }
  __syncthreads();

  // ---- p0: q = x @ Wa^T + ba ; wave w -> cols [64w, 64w+64) ----
  {
    f32x4 acc0[2][4] = {};
#pragma unroll
    for (int kc = 0; kc < 2; ++kc) {
      bf16x8 bw[4][4];
#pragma unroll
      for (int kk = 0; kk < 4; ++kk)
#pragma unroll
        for (int i = 0; i < 4; ++i) {
          const int ks = kc * 4 + kk;
          const int col = 64 * w + 16 * i + l16;
          bw[kk][i] = *(const bf16x8*)(Wa + (size_t)col * D_ + ks * 32 + quad * 8);
        }
#pragma unroll
      for (int kk = 0; kk < 4; ++kk) {
        const int ks = kc * 4 + kk;
        bf16x8 af[2];
#pragma unroll
        for (int m = 0; m < 2; ++m)
          af[m] = *(const bf16x8*)&xps[(16 * m + l16) * 264 + ks * 32 + quad * 8];
#pragma unroll
        for (int m = 0; m < 2; ++m)
#pragma unroll
          for (int i = 0; i < 4; ++i) acc0[m][i] = MFMA16(af[m], bw[kk][i], acc0[m][i]);
      }
    }
    // no mid-phase barrier: qs has no prior readers; xps readers are
    // protected by the post-epilogue barrier below (program order).
#pragma unroll
    for (int m = 0; m < 2; ++m)
#pragma unroll
      for (int i = 0; i < 4; ++i) {
        const int col = 64 * w + 16 * i + l16;
        const float bv = ba[col];
#pragma unroll
        for (int r = 0; r < 4; ++r)
          qs[(16 * m + quad * 4 + r) * 264 + col] = (bf16)(acc0[m][i][r] + bv);
      }
  }
  __syncthreads();   // qs ready; xps (x strip) dead -> becomes P

  // ---- p1: P = sigmoid(q @ xb^T), diag/adj mask -> xps bf16 ----
  float p[2][4] = {};
  const bf16* xbB = xb_in + (size_t)b * N_ * D_;
  for (int ct = 0; ct < 4; ++ct) {
    // prefetch all 16 B-operand loads for this ct before the MFMA chain
    bf16x8 bx[8][2];
#pragma unroll
    for (int ks = 0; ks < 8; ++ks)
#pragma unroll
      for (int jt = 0; jt < 2; ++jt) {
        const int gcol = ct * 128 + w * 32 + jt * 16 + l16;
        bx[ks][jt] = *(const bf16x8*)(xbB + (size_t)gcol * D_ + ks * 32 + quad * 8);
      }
    f32x4 acc1[2][2] = {};
#pragma unroll
    for (int ks = 0; ks < 8; ++ks) {
      bf16x8 af[2];
#pragma unroll
      for (int m = 0; m < 2; ++m)
        af[m] = *(const bf16x8*)&qs[(16 * m + l16) * 264 + ks * 32 + quad * 8];
#pragma unroll
      for (int m = 0; m < 2; ++m)
#pragma unroll
        for (int jt = 0; jt < 2; ++jt)
          acc1[m][jt] = MFMA16(af[m], bx[ks][jt], acc1[m][jt]);
    }
#pragma unroll
    for (int jt = 0; jt < 2; ++jt) {
      const int lcol = ct * 128 + w * 32 + jt * 16 + l16;
      const int piece = ct * 8 + w * 2 + jt;
#pragma unroll
      for (int m = 0; m < 2; ++m)
#pragma unroll
        for (int r = 0; r < 4; ++r) {
          const int row = 16 * m + quad * 4 + r;
          const int grow = row0 + row;
          float av;
          if (bits_in) {
            const unsigned short m16 = ((const unsigned short*)bits_s)[row * 32 + piece];
            av = (float)((m16 >> l16) & 1);
          } else {
            av = __builtin_nontemporal_load(
                adj + ((size_t)b * N_ + grow) * N_ + lcol);
          }
          const bool diag = (grow == lcol);
          if (bits_out) {  // layer 0: build bitmask
            const unsigned long long bal = __ballot(diag || av != 0.0f);
            if (l16 == 0)
              bits_out[((size_t)b * N_ + row0 + 16 * m + 4 * quad + r) * 32 + piece] =
                  (unsigned short)((bal >> (quad * 16)) & 0xFFFFull);
          }
          const float sg = sigmoidf_(acc1[m][jt][r]);
          const float v = diag ? (sg + 1e-5f) : sg * av;
          const bf16 bv = (bf16)v;
          xps[row * 520 + lcol] = bv;
          p[m][r] += (float)bv;
        }
    }
  }
#pragma unroll
  for (int m = 0; m < 2; ++m)
#pragma unroll
    for (int r = 0; r < 4; ++r) {
#pragma unroll
      for (int msk = 1; msk < 16; msk <<= 1) p[m][r] += __shfl_xor(p[m][r], msk, 64);
    }
  if (l16 == 0) {
#pragma unroll
    for (int m = 0; m < 2; ++m)
#pragma unroll
      for (int r = 0; r < 4; ++r) psum[w][16 * m + quad * 4 + r] = p[m][r];
  }
  __syncthreads();
  if (tid < 32)
    rinvs[tid] = 1.0f / (psum[0][tid] + psum[1][tid] + psum[2][tid] + psum[3][tid]);
  __syncthreads();

  // ---- p2: normalize; f32 kept in regs, bf16 back to xps ----
  const size_t abase = ((size_t)b * N_ + row0) * N_;
  f32x4 onv[16];
#pragma unroll
  for (int e = 0; e < 16; ++e) {
    const int idx = tid + e * 256;
    const int row = idx >> 7, c4 = (idx & 127) * 4;
    const float ri = rinvs[row];
    bf16x4 pv = *(const bf16x4*)&xps[row * 520 + c4];
    f32x4 nv;
    nv[0] = (float)pv[0] * ri; nv[1] = (float)pv[1] * ri;
    nv[2] = (float)pv[2] * ri; nv[3] = (float)pv[3] * ri;
    onv[e] = nv;
    bf16x4 o;
    o[0] = (bf16)nv[0]; o[1] = (bf16)nv[1]; o[2] = (bf16)nv[2]; o[3] = (bf16)nv[3];
    *(bf16x4*)&xps[row * 520 + c4] = o;
  }
  __syncthreads();
  // attls stores issued AFTER the barrier (fire-and-forget, nontemporal):
  // they drain under p3/p4 compute instead of stalling the barrier.
#pragma unroll
  for (int e = 0; e < 16; ++e) {
    const int idx = tid + e * 256;
    const int row = idx >> 7, c4 = (idx & 127) * 4;
    __builtin_nontemporal_store(onv[e],
        (f32x4*)(outA + abase + (size_t)row * N_ + c4));
  }

  // ---- p3: x' = P @ x (B = xT streamed), K = 512 ----
  f32x4 acc3[2][4] = {};
  const bf16* xTB = xT_in + (size_t)b * D_ * N_;
#pragma unroll
  for (int kc = 0; kc < 4; ++kc) {
    bf16x8 bt[4][4];
#pragma unroll
    for (int kk = 0; kk < 4; ++kk)
#pragma unroll
      for (int i = 0; i < 4; ++i) {
        const int ks = kc * 4 + kk;
        const int d = 64 * w + 16 * i + l16;
        bt[kk][i] = *(const bf16x8*)(xTB + (size_t)d * N_ + ks * 32 + quad * 8);
      }
#pragma unroll
    for (int kk = 0; kk < 4; ++kk) {
      const int ks = kc * 4 + kk;
      bf16x8 af[2];
#pragma unroll
      for (int m = 0; m < 2; ++m)
        af[m] = *(const bf16x8*)&xps[(16 * m + l16) * 520 + ks * 32 + quad * 8];
#pragma unroll
      for (int m = 0; m < 2; ++m)
#pragma unroll
        for (int i = 0; i < 4; ++i) acc3[m][i] = MFMA16(af[m], bt[kk][i], acc3[m][i]);
    }
  }
  // no mid barrier: qs (q) has no readers past p1 (all waves passed the
  // post-p2 barrier), so the epilogue may overwrite it directly.
#pragma unroll
  for (int m = 0; m < 2; ++m)
#pragma unroll
    for (int i = 0; i < 4; ++i) {
      const int d = 64 * w + 16 * i + l16;
#pragma unroll
      for (int r = 0; r < 4; ++r)
        qs[(16 * m + quad * 4 + r) * 264 + d] = (bf16)acc3[m][i][r];
    }
  __syncthreads();

  // ---- p4: h = relu(x' @ W0^T + b0) -> xps (stride 264) ----
  {
    f32x4 acc[2][4] = {};
#pragma unroll
    for (int kc = 0; kc < 2; ++kc) {
      bf16x8 bw[4][4];
#pragma unroll
      for (int kk = 0; kk < 4; ++kk)
#pragma unroll
        for (int i = 0; i < 4; ++i) {
          const int ks = kc * 4 + kk;
          const int col = 64 * w + 16 * i + l16;
          bw[kk][i] = *(const bf16x8*)(W0 + (size_t)col * D_ + ks * 32 + quad * 8);
        }
#pragma unroll
      for (int kk = 0; kk < 4; ++kk) {
        const int ks = kc * 4 + kk;
        bf16x8 af[2];
#pragma unroll
        for (int m = 0; m < 2; ++m)
          af[m] = *(const bf16x8*)&qs[(16 * m + l16) * 264 + ks * 32 + quad * 8];
#pragma unroll
        for (int m = 0; m < 2; ++m)
#pragma unroll
          for (int i = 0; i < 4; ++i) acc[m][i] = MFMA16(af[m], bw[kk][i], acc[m][i]);
      }
    }
    // no mid barrier: xps (P) has no readers past p3 (post-p3 barrier passed)
#pragma unroll
    for (int m = 0; m < 2; ++m)
#pragma unroll
      for (int i = 0; i < 4; ++i) {
        const int col = 64 * w + 16 * i + l16;
        const float bv = b0[col];
#pragma unroll
        for (int r = 0; r < 4; ++r)
          xps[(16 * m + quad * 4 + r) * 264 + col] = (bf16)fmaxf(acc[m][i][r] + bv, 0.0f);
      }
  }
  __syncthreads();

  // ---- p5: x = relu(h @ W1^T + b1) + resid(bf16) -> xb_out, xT_out ----
  {
    f32x4 acc[2][4] = {};
#pragma unroll
    for (int kc = 0; kc < 2; ++kc) {
      bf16x8 bw[4][4];
#pragma unroll
      for (int kk = 0; kk < 4; ++kk)
#pragma unroll
        for (int i = 0; i < 4; ++i) {
          const int ks = kc * 4 + kk;
          const int col = 64 * w + 16 * i + l16;
          bw[kk][i] = *(const bf16x8*)(W1 + (size_t)col * D_ + ks * 32 + quad * 8);
        }
#pragma unroll
      for (int kk = 0; kk < 4; ++kk) {
        const int ks = kc * 4 + kk;
        bf16x8 af[2];
#pragma unroll
        for (int m = 0; m < 2; ++m)
          af[m] = *(const bf16x8*)&xps[(16 * m + l16) * 264 + ks * 32 + quad * 8];
#pragma unroll
        for (int m = 0; m < 2; ++m)
#pragma unroll
          for (int i = 0; i < 4; ++i) acc[m][i] = MFMA16(af[m], bw[kk][i], acc[m][i]);
      }
    }
#pragma unroll
    for (int m = 0; m < 2; ++m)
#pragma unroll
      for (int i = 0; i < 4; ++i) {
        const int d = 64 * w + 16 * i + l16;
        const float bv = b1[d];
        // residual read via xT layout: 4 rows, same d -> one bf16x4
        const bf16x4 x0v = *(const bf16x4*)&xT_in[((size_t)(b * D_ + d)) * N_ +
                                                  row0 + 16 * m + quad * 4];
        bf16x4 tv;
#pragma unroll
        for (int r = 0; r < 4; ++r) {
          const size_t R = (size_t)b * N_ + row0 + 16 * m + quad * 4 + r;
          const float t = fmaxf(acc[m][i][r] + bv, 0.0f) + (float)x0v[r];
          const bf16 tb = (bf16)t;
          xb_out[R * D_ + d] = tb;
          tv[r] = tb;
        }
        *(bf16x4*)&xT_out[((size_t)(b * D_ + d)) * N_ + row0 + 16 * m + quad * 4] = tv;
      }
  }
}

// ---------------------------------------------------------------------------
// final_proj: out = x @ Wf^T + bf (f32), per 32-row strip, B streamed.
// Same XCD swizzle as gat_layer so layer-3's xb writes are L2-local here.
// ---------------------------------------------------------------------------
__global__ __launch_bounds__(256, 4) void final_proj(
    const bf16* __restrict__ xin, const bf16* __restrict__ Wf,
    const float* __restrict__ bfv, float* __restrict__ outX)
{
  __shared__ bf16 as_[32 * 264];
  const int tid = threadIdx.x, w = tid >> 6, lane = tid & 63;
  const int l16 = lane & 15, quad = lane >> 4;
  const int wg = blockIdx.x;
  const int lid = (wg & 7) * 128 + (wg >> 3);
  const int row0g = lid * 32;
#pragma unroll
  for (int e = 0; e < 4; ++e) {
    const int cc = tid + e * 256;
    const int r = cc >> 5, cg = cc & 31;
    *(bf16x8*)&as_[r * 264 + cg * 8] =
        *(const bf16x8*)(xin + ((size_t)(row0g + r)) * D_ + cg * 8);
  }
  __syncthreads();
  f32x4 acc[2][4] = {};
#pragma unroll
  for (int kc = 0; kc < 2; ++kc) {
    bf16x8 bw[4][4];
#pragma unroll
    for (int kk = 0; kk < 4; ++kk)
#pragma unroll
      for (int i = 0; i < 4; ++i) {
        const int ks = kc * 4 + kk;
        const int col = 64 * w + 16 * i + l16;
        bw[kk][i] = *(const bf16x8*)(Wf + (size_t)col * D_ + ks * 32 + quad * 8);
      }
#pragma unroll
    for (int kk = 0; kk < 4; ++kk) {
      const int ks = kc * 4 + kk;
      bf16x8 af[2];
#pragma unroll
      for (int m = 0; m < 2; ++m)
        af[m] = *(const bf16x8*)&as_[(16 * m + l16) * 264 + ks * 32 + quad * 8];
#pragma unroll
      for (int m = 0; m < 2; ++m)
#pragma unroll
        for (int i = 0; i < 4; ++i) acc[m][i] = MFMA16(af[m], bw[kk][i], acc[m][i]);
    }
  }
#pragma unroll
  for (int m = 0; m < 2; ++m)
#pragma unroll
    for (int i = 0; i < 4; ++i) {
      const int col = 64 * w + 16 * i + l16;
      const float bv = bfv[col];
#pragma unroll
      for (int r = 0; r < 4; ++r) {
        const size_t R = (size_t)row0g + 16 * m + quad * 4 + r;
        __builtin_nontemporal_store(acc[m][i][r] + bv, outX + R * D_ + col);
      }
    }
}

// ---------------------------------------------------------------------------
// init: x -> xb bf16, xT bf16 (LDS 32x32 transpose). Batch-contiguous XCD
// swizzle matching gat_layer so layer 0's reads are L2-local.
// ---------------------------------------------------------------------------
__global__ __launch_bounds__(256) void init_x(
    const float* __restrict__ x, bf16* __restrict__ xb, bf16* __restrict__ xT)
{
  __shared__ float t[32 * 33];
  const int tid = threadIdx.x;
  const int wg = blockIdx.x;                 // 0..8191
  const int lid = (wg & 7) * 1024 + (wg >> 3);
  const int b = lid >> 7, rem = lid & 127;   // 128 blocks per batch
  const int dt = rem >> 4, nt = rem & 15;
#pragma unroll
  for (int e = 0; e < 4; ++e) {
    const int idx = tid + e * 256;
    const int r = idx >> 5, c = idx & 31;
    const size_t g = ((size_t)(b * N_ + nt * 32 + r)) * D_ + dt * 32 + c;
    const float v = x[g];
    xb[g] = (bf16)v;
    t[r * 33 + c] = v;
  }
  __syncthreads();
#pragma unroll
  for (int e = 0; e < 4; ++e) {
    const int idx = tid + e * 256;
    const int r = idx >> 5, c = idx & 31;
    xT[((size_t)(b * D_ + dt * 32 + r)) * N_ + nt * 32 + c] = (bf16)t[c * 33 + r];
  }
}

__global__ __launch_bounds__(256) void cvt_bf16(
    const float* __restrict__ src, bf16* __restrict__ dst, int n4)
{
  const int i = blockIdx.x * 256 + threadIdx.x;
  if (i < n4) {
    const float4 v = ((const float4*)src)[i];
    bf16x4 o;
    o[0] = (bf16)v.x; o[1] = (bf16)v.y; o[2] = (bf16)v.z; o[3] = (bf16)v.w;
    ((bf16x4*)dst)[i] = o;
  }
}

extern "C" void kernel_launch(void* const* d_in, const int* in_sizes, int n_in,
                              void* d_out, int out_size, void* d_ws, size_t ws_size,
                              hipStream_t stream)
{
  const float* x_in  = (const float*)d_in[0];
  const float* adj   = (const float*)d_in[1];
  const float* wattn = (const float*)d_in[2];
  const float* battn = (const float*)d_in[3];
  const float* w0    = (const float*)d_in[4];
  const float* b0    = (const float*)d_in[5];
  const float* w1    = (const float*)d_in[6];
  const float* b1    = (const float*)d_in[7];
  const float* wf    = (const float*)d_in[8];
  const float* bfin  = (const float*)d_in[9];

  float* out_x    = (float*)d_out;                     // [B,N,D] f32 (final only)
  float* out_attn = out_x + (size_t)B_ * N_ * D_;      // [L,B,N,N]

  const size_t XBN = (size_t)B_ * N_ * D_;
  bf16* wb  = (bf16*)d_ws;                             // 13 * D*D weights
  bf16* xb0 = wb + 13 * (D_ * D_);
  bf16* xT0 = xb0 + XBN;
  bf16* xb1 = xT0 + XBN;
  bf16* xT1 = xb1 + XBN;
  unsigned short* bits = (unsigned short*)(xT1 + XBN); // [B,N,32] uint16

  const int DD2 = D_ * D_;
  const int Mfull = B_ * N_;  // 32768

  cvt_bf16<<<dim3((L_ * DD2 / 4 + 255) / 256), 256, 0, stream>>>(wattn, wb, L_ * DD2 / 4);
  cvt_bf16<<<dim3((L_ * DD2 / 4 + 255) / 256), 256, 0, stream>>>(w0, wb + 4 * DD2, L_ * DD2 / 4);
  cvt_bf16<<<dim3((L_ * DD2 / 4 + 255) / 256), 256, 0, stream>>>(w1, wb + 8 * DD2, L_ * DD2 / 4);
  cvt_bf16<<<dim3((DD2 / 4 + 255) / 256), 256, 0, stream>>>(wf, wb + 12 * DD2, DD2 / 4);

  init_x<<<dim3((N_ / 32) * (D_ / 32) * B_), 256, 0, stream>>>(x_in, xb0, xT0);

  bf16* xbs[2] = {xb0, xb1};
  bf16* xTs[2] = {xT0, xT1};
  for (int l = 0; l < L_; ++l) {
    const int pi = l & 1, po = 1 - pi;
    gat_layer<<<dim3((N_ / 32) * B_), 256, 0, stream>>>(
        xbs[pi], xTs[pi], xbs[po], xTs[po],
        wb + l * DD2, battn + l * D_,
        wb + (4 + l) * DD2, b0 + l * D_,
        wb + (8 + l) * DD2, b1 + l * D_,
        adj, (l == 0) ? nullptr : bits, (l == 0) ? bits : nullptr,
        out_attn + (size_t)l * B_ * N_ * N_);
  }
  final_proj<<<dim3(Mfull / 32), 256, 0, stream>>>(xbs[0], wb + 12 * DD2, bfin, out_x);
}